// Round 2
// baseline (197.009 us; speedup 1.0000x reference)
//
#include <hip/hip_runtime.h>
#include <math.h>

// DMPNet fused kernel, MI355X.
// Closed-form DMP: y_T = a_T*y0 + h_T*0.05 + c_T*goal + (goal-y0)*(w . V_T)
// Table (11 x 8 floats) computed per-launch by a tiny setup kernel into d_ws.

// ---------------- setup kernel: build coefficient table ----------------
// tbl[tt*8 + 0] = a_T   (y0 coefficient,  (A^T)_00)
// tbl[tt*8 + 1] = c_T   (goal coefficient, 0.5625 * sum_{k<T} h_k)
// tbl[tt*8 + 2] = d_T   (constant term, h_T * z0 with z0 = 0.05)
// tbl[tt*8 + 3+i] = V_T[i] = 0.01 * sum_{s=1..T} h_{T-s} * v_s[i]
__global__ void dmp_setup_kernel(float* __restrict__ tbl) {
    __shared__ float vv[101][5];
    __shared__ float hh[101];
    __shared__ float aa[101];
    const int t = threadIdx.x;
    if (t <= 100) {
        // A^t by square-and-multiply, A = [[1, 0.01], [-0.5625, 0.85]]
        float m00 = 1.f, m01 = 0.f, m10 = 0.f, m11 = 1.f;
        float p00 = 1.f, p01 = 0.01f, p10 = -0.5625f, p11 = 0.85f;
        int e = t;
        while (e) {
            if (e & 1) {
                const float n00 = m00 * p00 + m01 * p10;
                const float n01 = m00 * p01 + m01 * p11;
                const float n10 = m10 * p00 + m11 * p10;
                const float n11 = m10 * p01 + m11 * p11;
                m00 = n00; m01 = n01; m10 = n10; m11 = n11;
            }
            const float q00 = p00 * p00 + p01 * p10;
            const float q01 = p00 * p01 + p01 * p11;
            const float q10 = p10 * p00 + p11 * p10;
            const float q11 = p10 * p01 + p11 * p11;
            p00 = q00; p01 = q01; p10 = q10; p11 = q11;
            e >>= 1;
        }
        hh[t] = m01;
        aa[t] = m00;
        if (t >= 1) {
            // canonical system value x_s = 0.99^s (sequential, matching ref)
            float xs = 1.0f;
            for (int i = 0; i < t; ++i) xs *= 0.99f;
            float psi[5];
            float sum = 0.f;
#pragma unroll
            for (int i = 0; i < 5; ++i) {
                const float ci = expf(-0.25f * (float)i);          // c_i
                const float s2 = 11.180339887498949f / ci;          // sigma2_i = 5^1.5 / c_i
                const float dxc = xs - ci;
                psi[i] = expf(-0.5f * dxc * dxc / s2);
                sum += psi[i];
            }
#pragma unroll
            for (int i = 0; i < 5; ++i) vv[t][i] = psi[i] * xs / sum;
        }
    }
    __syncthreads();
    if (t < 66) {
        const int tt = t / 6, q = t - tt * 6, T = 10 * tt;
        if (q == 0) {
            float cg = 0.f;
            for (int k = 0; k < T; ++k) cg += hh[k];
            tbl[tt * 8 + 0] = aa[T];
            tbl[tt * 8 + 1] = 0.5625f * cg;
            tbl[tt * 8 + 2] = hh[T] * 0.05f;   // z0 = dy0 * TAU = 0.05
        } else {
            const int i = q - 1;
            float V = 0.f;
            for (int s = 1; s <= T; ++s) V += hh[T - s] * vv[s][i];
            tbl[tt * 8 + 3 + i] = 0.01f * V;
        }
    }
}

// ---------------- main kernel ----------------
// Grid 1024 x 64 threads. One wave per block; wave owns 64 rows, full K=256.
// x staged through transposed LDS tile in 32-k chunks (coalesced global loads,
// conflict-free LDS reads), W broadcast via SGPRs (wave-uniform k), epilogue
// fully in-register per lane (lane == row).
__global__ __launch_bounds__(64) void dmp_main_kernel(
    const float* __restrict__ x,      // [65536, 256]
    const float* __restrict__ state,  // [65536, 7]
    const float* __restrict__ W,      // [256, 42]
    const float* __restrict__ bias,   // [42]
    const float* __restrict__ tbl,    // [11, 8]
    float* __restrict__ out)          // [65536, 11, 7]
{
    __shared__ float xt[32 * 65];     // [k][row], stride 65 -> 8320 B

    const int l   = threadIdx.x;      // lane == local row
    const int blk = blockIdx.x;
    const size_t row0 = (size_t)blk * 64;

    const int rl = l >> 3;            // staging: sub-row 0..7
    const int q  = l & 7;             // staging: float4 slot 0..7

    float acc[42];
#pragma unroll
    for (int ch = 0; ch < 42; ++ch) acc[ch] = 0.f;

    const float* xb = x + row0 * 256;

    // prologue: prefetch chunk 0 (8 float4/lane; lanes 0-7 cover 128 B of a row)
    float4 s[8];
#pragma unroll
    for (int it = 0; it < 8; ++it)
        s[it] = *reinterpret_cast<const float4*>(xb + (size_t)(it * 8 + rl) * 256 + q * 4);

#pragma unroll 1
    for (int c = 0; c < 8; ++c) {
        // stage chunk c into LDS, transposed: xt[k][row]
#pragma unroll
        for (int it = 0; it < 8; ++it) {
            const int rr = it * 8 + rl;
            xt[(q * 4 + 0) * 65 + rr] = s[it].x;
            xt[(q * 4 + 1) * 65 + rr] = s[it].y;
            xt[(q * 4 + 2) * 65 + rr] = s[it].z;
            xt[(q * 4 + 3) * 65 + rr] = s[it].w;
        }
        // issue prefetch of chunk c+1 before computing (overlaps HBM latency)
        if (c < 7) {
#pragma unroll
            for (int it = 0; it < 8; ++it)
                s[it] = *reinterpret_cast<const float4*>(
                    xb + (size_t)(it * 8 + rl) * 256 + ((c + 1) * 32 + q * 4));
        }
        __syncthreads();   // 1-wave block: cheap; orders ds_write -> ds_read

        // compute chunk c: k wave-uniform -> W rows come in via s_load broadcast
#pragma unroll 4
        for (int kk = 0; kk < 32; ++kk) {
            const float xv = xt[kk * 65 + l];          // bank = lane: conflict-free
            const float* Wr = W + (size_t)((c << 5) + kk) * 42;
#pragma unroll
            for (int ch = 0; ch < 42; ++ch) acc[ch] = fmaf(xv, Wr[ch], acc[ch]);
        }
        __syncthreads();   // protect xt from next chunk's writes
    }

    // ---------------- epilogue: closed-form DMP, all in registers ----------------
    const float* st = state + (row0 + l) * 7;
    float* ob = out + (row0 + l) * 77;

#pragma unroll
    for (int d = 0; d < 7; ++d) {
        const float goal = acc[d] + bias[d];
        const float w0 = acc[7 + 5 * d + 0] + bias[7 + 5 * d + 0];
        const float w1 = acc[7 + 5 * d + 1] + bias[7 + 5 * d + 1];
        const float w2 = acc[7 + 5 * d + 2] + bias[7 + 5 * d + 2];
        const float w3 = acc[7 + 5 * d + 3] + bias[7 + 5 * d + 3];
        const float w4 = acc[7 + 5 * d + 4] + bias[7 + 5 * d + 4];
        const float y0 = st[d];
        const float gp = goal - y0;
#pragma unroll
        for (int tt = 0; tt < 11; ++tt) {
            const float a  = tbl[tt * 8 + 0];
            const float cg = tbl[tt * 8 + 1];
            const float dc = tbl[tt * 8 + 2];
            float p = tbl[tt * 8 + 3] * w0;
            p = fmaf(tbl[tt * 8 + 4], w1, p);
            p = fmaf(tbl[tt * 8 + 5], w2, p);
            p = fmaf(tbl[tt * 8 + 6], w3, p);
            p = fmaf(tbl[tt * 8 + 7], w4, p);
            float y = fmaf(a, y0, dc);
            y = fmaf(cg, goal, y);
            y = fmaf(gp, p, y);
            ob[tt * 7 + d] = y;
        }
    }
}

extern "C" void kernel_launch(void* const* d_in, const int* in_sizes, int n_in,
                              void* d_out, int out_size, void* d_ws, size_t ws_size,
                              hipStream_t stream) {
    const float* x     = (const float*)d_in[0];  // [65536,256]
    const float* state = (const float*)d_in[1];  // [65536,7]
    const float* W     = (const float*)d_in[2];  // [256,42]
    const float* b     = (const float*)d_in[3];  // [42]
    float* tbl = (float*)d_ws;                   // 88 floats
    float* out = (float*)d_out;

    dmp_setup_kernel<<<1, 128, 0, stream>>>(tbl);
    dmp_main_kernel<<<1024, 64, 0, stream>>>(x, state, W, b, tbl, out);
}

// Round 3
// 193.258 us; speedup vs baseline: 1.0194x; 1.0194x over previous
//
#include <hip/hip_runtime.h>
#include <math.h>

// DMPNet fused, MI355X. Closed-form DMP:
//   y_T = a_T*y0 + h_T*z0 + c_T*goal + (goal-y0)*(w . V_T)
// Single kernel: per-block table build -> coalesced LDS-staged GEMM with
// wave-level K-split + 2-round LDS reduction -> in-register epilogue on wave 0
// -> coalesced float4 output flush.
//
// LDS layout (floats), total 10114 = 40456 B (4 blocks/CU = 163840 B exactly):
//   XT = 0     [64][65]  transposed x chunk (reused as OB[64*77] in epilogue)
//   P2 = 4160  [42][129] cross-wave partials (reused: VV/HH/AA scratch early)
//   TB = 9578  [88]      DMP coefficient table
//   SS = 9666  [448]     staged state block

__global__ __launch_bounds__(256) void dmp_fused_kernel(
    const float* __restrict__ x,      // [65536,256]
    const float* __restrict__ state,  // [65536,7]
    const float* __restrict__ W,      // [256,42]
    const float* __restrict__ bias,   // [42]
    float* __restrict__ out)          // [65536,11,7]
{
    constexpr int XT = 0;
    constexpr int P2 = 4160;
    constexpr int VV = 4160;   // [101][5] (overlays P2, dead before reduction)
    constexpr int HH = 4672;   // [101]
    constexpr int AA = 4928;   // [101]
    constexpr int TB = 9578;   // [88]
    constexpr int SS = 9666;   // [448]
    __shared__ float L[10114];

    const int tid  = threadIdx.x;
    const int wave = __builtin_amdgcn_readfirstlane(tid >> 6);
    const int lane = tid & 63;
    const size_t row0 = (size_t)blockIdx.x * 64;

    // -------- prefetch chunk 0 (latency overlaps table build) --------
    float4 p[4];
#pragma unroll
    for (int it = 0; it < 4; ++it) {
        const int f = it * 256 + tid;
        p[it] = *(const float4*)(x + (row0 + (f >> 4)) * 256 + (f & 15) * 4);
    }

    // -------- DMP coefficient table (per-block, in LDS) --------
    if (tid <= 100) {
        // A^t by square-and-multiply, A = [[1, 0.01], [-0.5625, 0.85]]
        float m00 = 1.f, m01 = 0.f, m10 = 0.f, m11 = 1.f;
        float q00 = 1.f, q01 = 0.01f, q10 = -0.5625f, q11 = 0.85f;
        int e = tid;
        while (e) {
            if (e & 1) {
                const float n00 = m00 * q00 + m01 * q10;
                const float n01 = m00 * q01 + m01 * q11;
                const float n10 = m10 * q00 + m11 * q10;
                const float n11 = m10 * q01 + m11 * q11;
                m00 = n00; m01 = n01; m10 = n10; m11 = n11;
            }
            const float r00 = q00 * q00 + q01 * q10;
            const float r01 = q00 * q01 + q01 * q11;
            const float r10 = q10 * q00 + q11 * q10;
            const float r11 = q10 * q01 + q11 * q11;
            q00 = r00; q01 = r01; q10 = r10; q11 = r11;
            e >>= 1;
        }
        L[HH + tid] = m01;
        L[AA + tid] = m00;
        if (tid >= 1) {
            float xs = 1.0f;                       // x_s = 0.99^s (sequential)
            for (int i = 0; i < tid; ++i) xs *= 0.99f;
            float psi[5], sum = 0.f;
#pragma unroll
            for (int i = 0; i < 5; ++i) {
                const float ci = expf(-0.25f * (float)i);
                const float s2 = 11.180339887498949f / ci;   // 5^1.5 / c_i
                const float dxc = xs - ci;
                psi[i] = expf(-0.5f * dxc * dxc / s2);
                sum += psi[i];
            }
#pragma unroll
            for (int i = 0; i < 5; ++i) L[VV + tid * 5 + i] = psi[i] * xs / sum;
        }
    }
    __syncthreads();
    if (tid < 66) {
        const int tt = tid / 6, q = tid - tt * 6, T = 10 * tt;
        if (q == 0) {
            float cg = 0.f;
            for (int k = 0; k < T; ++k) cg += L[HH + k];
            L[TB + tt * 8 + 0] = L[AA + T];
            L[TB + tt * 8 + 1] = 0.5625f * cg;
            L[TB + tt * 8 + 2] = L[HH + T] * 0.05f;   // z0 = 0.05
        } else {
            const int i = q - 1;
            float V = 0.f;
            for (int s = 1; s <= T; ++s) V += L[HH + T - s] * L[VV + s * 5 + i];
            L[TB + tt * 8 + 3 + i] = 0.01f * V;
        }
    }
    // (no barrier needed here: in-loop barriers below order TB/VV vs later use)

    // -------- GEMM: 4 chunks of 64 k; wave w computes k_local in [16w,16w+16) --
    float acc[42];
#pragma unroll
    for (int ch = 0; ch < 42; ++ch) acc[ch] = 0.f;
    const int w16 = wave * 16;

#pragma unroll 1
    for (int c = 0; c < 4; ++c) {
        // stage chunk c transposed: XT[k][row], stride 65 (2-way banks = free)
#pragma unroll
        for (int it = 0; it < 4; ++it) {
            const int f = it * 256 + tid;
            const int row = f >> 4, kq = f & 15;
            L[XT + (4 * kq + 0) * 65 + row] = p[it].x;
            L[XT + (4 * kq + 1) * 65 + row] = p[it].y;
            L[XT + (4 * kq + 2) * 65 + row] = p[it].z;
            L[XT + (4 * kq + 3) * 65 + row] = p[it].w;
        }
        // prefetch chunk c+1 (overlaps compute below)
        if (c < 3) {
#pragma unroll
            for (int it = 0; it < 4; ++it) {
                const int f = it * 256 + tid;
                p[it] = *(const float4*)(x + (row0 + (f >> 4)) * 256 +
                                         (c + 1) * 64 + (f & 15) * 4);
            }
        }
        __syncthreads();
#pragma unroll
        for (int kk = 0; kk < 16; ++kk) {
            const float xv = L[XT + (w16 + kk) * 65 + lane];
            const float* Wr = W + (size_t)(c * 64 + w16 + kk) * 42;  // wave-uniform
#pragma unroll
            for (int ch = 0; ch < 42; ++ch) acc[ch] = fmaf(xv, Wr[ch], acc[ch]);
        }
        __syncthreads();
    }

    // -------- stage state (coalesced) + 2-round cross-wave reduction --------
    L[SS + tid] = state[row0 * 7 + tid];
    if (tid < 192) L[SS + 256 + tid] = state[row0 * 7 + 256 + tid];
    if (wave >= 2) {
#pragma unroll
        for (int ch = 0; ch < 42; ++ch)
            L[P2 + ch * 129 + (wave - 2) * 65 + lane] = acc[ch];
    }
    __syncthreads();
    if (wave < 2) {
#pragma unroll
        for (int ch = 0; ch < 42; ++ch)
            acc[ch] += L[P2 + ch * 129 + wave * 65 + lane];
    }
    __syncthreads();
    if (wave == 1) {
#pragma unroll
        for (int ch = 0; ch < 42; ++ch) L[P2 + ch * 129 + lane] = acc[ch];
    }
    __syncthreads();

    // -------- epilogue on wave 0 (lane == row), write OB into LDS --------
    if (wave == 0) {
#pragma unroll
        for (int ch = 0; ch < 42; ++ch) acc[ch] += L[P2 + ch * 129 + lane];
#pragma unroll
        for (int d = 0; d < 7; ++d) {
            const float goal = acc[d] + bias[d];
            const float w0 = acc[7 + 5 * d + 0] + bias[7 + 5 * d + 0];
            const float w1 = acc[7 + 5 * d + 1] + bias[7 + 5 * d + 1];
            const float w2 = acc[7 + 5 * d + 2] + bias[7 + 5 * d + 2];
            const float w3 = acc[7 + 5 * d + 3] + bias[7 + 5 * d + 3];
            const float w4 = acc[7 + 5 * d + 4] + bias[7 + 5 * d + 4];
            const float y0 = L[SS + lane * 7 + d];
            const float gp = goal - y0;
#pragma unroll
            for (int tt = 0; tt < 11; ++tt) {
                const float a  = L[TB + tt * 8 + 0];
                const float cg = L[TB + tt * 8 + 1];
                const float dc = L[TB + tt * 8 + 2];
                float pf = L[TB + tt * 8 + 3] * w0;
                pf = fmaf(L[TB + tt * 8 + 4], w1, pf);
                pf = fmaf(L[TB + tt * 8 + 5], w2, pf);
                pf = fmaf(L[TB + tt * 8 + 6], w3, pf);
                pf = fmaf(L[TB + tt * 8 + 7], w4, pf);
                float y = fmaf(a, y0, dc);
                y = fmaf(cg, goal, y);
                y = fmaf(gp, pf, y);
                L[lane * 77 + tt * 7 + d] = y;   // OB overlays XT (+P2 head, dead)
            }
        }
    }
    __syncthreads();

    // -------- coalesced float4 flush: 64 rows x 77 = 1232 float4 --------
#pragma unroll
    for (int it = 0; it < 5; ++it) {
        const int idx = it * 256 + tid;
        if (idx < 1232) {
            const float4 v = *(const float4*)&L[idx * 4];
            *(float4*)(out + row0 * 77 + (size_t)idx * 4) = v;
        }
    }
}

extern "C" void kernel_launch(void* const* d_in, const int* in_sizes, int n_in,
                              void* d_out, int out_size, void* d_ws, size_t ws_size,
                              hipStream_t stream) {
    const float* x     = (const float*)d_in[0];  // [65536,256]
    const float* state = (const float*)d_in[1];  // [65536,7]
    const float* W     = (const float*)d_in[2];  // [256,42]
    const float* b     = (const float*)d_in[3];  // [42]
    float* out = (float*)d_out;

    dmp_fused_kernel<<<1024, 256, 0, stream>>>(x, state, W, b, out);
}

// Round 4
// 125.236 us; speedup vs baseline: 1.5731x; 1.5431x over previous
//
#include <hip/hip_runtime.h>
#include <math.h>

// DMPNet fused, MI355X. Closed-form DMP:
//   y_T = a_T*y0 + h_T*z0 + c_T*goal + (goal-y0)*(w . V_T)
// The 11x8 coefficient table is input-independent -> computed at COMPILE TIME
// (constexpr, double precision) and folded into the epilogue as literals.
//
// Kernel: 1024 blocks x 256 threads, block owns 64 rows.
// GEMM: x staged coalesced -> transposed LDS tiles (32 k, double-buffered,
// ONE barrier per chunk); W rows read wave-uniformly (k uniform per wave) ->
// SGPR broadcast, 1 v_fma per MAC; wave w owns k%32 in [8w,8w+8).
// Reduce: 2-round LDS (42ch x 64row x 2 sets, bias folded in).
// Epilogue: 448 items (row,dof) spread over all threads, 2 passes of 32 rows
// through an OB overlay -> coalesced float4 output flush.
//
// __launch_bounds__(256,4): LDS (38480 B) caps at 4 blocks/CU anyway; allow
// 128 VGPRs so the compiler can pipeline loads (R3 regression root cause:
// VGPR=68 -> zero prefetch depth, serialized waitcnt).

// ---------------- compile-time DMP coefficient table ----------------
constexpr double dexp(double z) {
    double t = z / 64.0;
    double s = 1.0, term = 1.0;
    for (int n = 1; n <= 14; ++n) { term *= t / (double)n; s += term; }
    for (int i = 0; i < 6; ++i) s *= s;   // ^64
    return s;
}

struct Tbl { float v[88]; };

constexpr Tbl make_tbl() {
    Tbl T{};
    double c[5] = {}, s2[5] = {};
    for (int i = 0; i < 5; ++i) {
        c[i]  = dexp(-0.25 * (double)i);
        s2[i] = 11.180339887498949 / c[i];       // 5^1.5 / c_i
    }
    double hh[101] = {}, aa[101] = {};
    // A^t, A = [[1, 0.01], [-0.5625, 0.85]] (sequential powers)
    double m00 = 1, m01 = 0, m10 = 0, m11 = 1;
    for (int t = 0; t <= 100; ++t) {
        hh[t] = m01; aa[t] = m00;
        const double n00 = m00 - 0.5625 * m01;
        const double n01 = 0.01 * m00 + 0.85 * m01;
        const double n10 = m10 - 0.5625 * m11;
        const double n11 = 0.01 * m10 + 0.85 * m11;
        m00 = n00; m01 = n01; m10 = n10; m11 = n11;
    }
    double vv[101][5] = {};
    double xs = 1.0;
    for (int s = 1; s <= 100; ++s) {
        xs *= 0.99;                               // canonical x_s = 0.99^s
        double psi[5] = {}, sum = 0.0;
        for (int i = 0; i < 5; ++i) {
            const double d = xs - c[i];
            psi[i] = dexp(-0.5 * d * d / s2[i]);
            sum += psi[i];
        }
        for (int i = 0; i < 5; ++i) vv[s][i] = psi[i] * xs / sum;
    }
    for (int tt = 0; tt < 11; ++tt) {
        const int T10 = 10 * tt;
        double cg = 0.0;
        for (int k = 0; k < T10; ++k) cg += hh[k];
        T.v[tt * 8 + 0] = (float)aa[T10];
        T.v[tt * 8 + 1] = (float)(0.5625 * cg);
        T.v[tt * 8 + 2] = (float)(hh[T10] * 0.05);   // z0 = dy0*TAU = 0.05
        for (int i = 0; i < 5; ++i) {
            double V = 0.0;
            for (int s = 1; s <= T10; ++s) V += hh[T10 - s] * vv[s][i];
            T.v[tt * 8 + 3 + i] = (float)(0.01 * V);
        }
    }
    return T;
}

constexpr Tbl TBL = make_tbl();

// ---------------- LDS layout (floats), total 9620 = 38480 B ----------------
//  XT0 = 0     [32][65]  x tile buf 0   (epilogue: OB[32*77]=2464 overlays XT)
//  XT1 = 2080  [32][65]  x tile buf 1
//  P   = 4160  [2][42][65]  cross-wave partial sums (bias folded into set 0)
#define XT0 0
#define XT1 2080
#define PP  4160

__global__ __launch_bounds__(256, 4) void dmp_fused_kernel(
    const float* __restrict__ x,      // [65536,256]
    const float* __restrict__ state,  // [65536,7]
    const float* __restrict__ W,      // [256,42]
    const float* __restrict__ bias,   // [42]
    float* __restrict__ out)          // [65536,11,7]
{
    __shared__ float L[9620];

    const int tid  = threadIdx.x;
    const int wave = __builtin_amdgcn_readfirstlane(tid >> 6);
    const int lane = tid & 63;
    const size_t row0 = (size_t)blockIdx.x * 64;

    const int srow0 = tid >> 3;          // staging row for f0 = tid      (0..31)
    const int q4    = (tid & 7) * 4;     // staging k-offset (float4 slot)
    const float* xb = x + row0 * 256;

    float4 ra, rb;                       // in-flight tile (2 float4 / thread)

    // prologue: load tile 0, stage it, load tile 1
    ra = *(const float4*)(xb + (size_t)srow0 * 256 + q4);
    rb = *(const float4*)(xb + (size_t)(srow0 + 32) * 256 + q4);

    float acc[42];
#pragma unroll
    for (int ch = 0; ch < 42; ++ch) acc[ch] = 0.f;

    // stage tile 0 -> XT0   (banks: (4*(tid&7)+j)*65+row -> exact 2-way, free)
    {
        const int b0 = XT0 + q4 * 65 + srow0;
        L[b0]            = ra.x; L[b0 + 65]       = ra.y;
        L[b0 + 130]      = ra.z; L[b0 + 195]      = ra.w;
        const int b1 = XT0 + q4 * 65 + srow0 + 32;
        L[b1]            = rb.x; L[b1 + 65]       = rb.y;
        L[b1 + 130]      = rb.z; L[b1 + 195]      = rb.w;
    }
    ra = *(const float4*)(xb + (size_t)srow0 * 256 + 32 + q4);
    rb = *(const float4*)(xb + (size_t)(srow0 + 32) * 256 + 32 + q4);
    __syncthreads();

    const int kw = wave * 8;             // this wave's k-slice within a chunk

#pragma unroll 1
    for (int c = 0; c < 8; ++c) {
        const int cur = (c & 1) ? XT1 : XT0;
        const int nxt = (c & 1) ? XT0 : XT1;

        // 1) stage tile c+1 (regs -> other buffer); frees regs
        if (c < 7) {
            const int b0 = nxt + q4 * 65 + srow0;
            L[b0]       = ra.x; L[b0 + 65]  = ra.y;
            L[b0 + 130] = ra.z; L[b0 + 195] = ra.w;
            const int b1 = nxt + q4 * 65 + srow0 + 32;
            L[b1]       = rb.x; L[b1 + 65]  = rb.y;
            L[b1 + 130] = rb.z; L[b1 + 195] = rb.w;
        }
        // 2) issue loads for tile c+2 (long latency, overlaps compute)
        if (c < 6) {
            const int ko = (c + 2) * 32 + q4;
            ra = *(const float4*)(xb + (size_t)srow0 * 256 + ko);
            rb = *(const float4*)(xb + (size_t)(srow0 + 32) * 256 + ko);
        }
        // 3) compute chunk c: k wave-uniform -> W via s_load broadcast
        const float* Wb = W + (size_t)(c * 32 + kw) * 42;
#pragma unroll
        for (int j = 0; j < 8; ++j) {
            const float xv = L[cur + (kw + j) * 65 + lane];
#pragma unroll
            for (int ch = 0; ch < 42; ++ch)
                acc[ch] = fmaf(xv, Wb[j * 42 + ch], acc[ch]);
        }
        __syncthreads();
    }

    // -------- reduction: waves 0,1 write (bias folded in set 0); 2,3 RMW ----
    if (wave < 2) {
#pragma unroll
        for (int ch = 0; ch < 42; ++ch) {
            const float bv = (wave == 0) ? bias[ch] : 0.f;   // bias via s_load
            L[PP + (wave * 42 + ch) * 65 + lane] = acc[ch] + bv;
        }
    }
    __syncthreads();
    if (wave >= 2) {
#pragma unroll
        for (int ch = 0; ch < 42; ++ch) {
            const int idx = PP + ((wave - 2) * 42 + ch) * 65 + lane;
            L[idx] += acc[ch];
        }
    }
    __syncthreads();

    // -------- epilogue: 448 (row,dof) items, 2 passes of 32 rows ----------
#pragma unroll 1
    for (int pass = 0; pass < 2; ++pass) {
        if (tid < 224) {
            const int item = pass * 224 + tid;
            const int row  = item / 7;          // global local-row 0..63
            const int d    = item - row * 7;
            const int lrow = row - pass * 32;   // 0..31

            const int ch0 = d;
            const int chw = 7 + 5 * d;
            const float goal = L[PP + ch0 * 65 + row] + L[PP + (42 + ch0) * 65 + row];
            float w_[5];
#pragma unroll
            for (int i = 0; i < 5; ++i)
                w_[i] = L[PP + (chw + i) * 65 + row] + L[PP + (42 + chw + i) * 65 + row];

            const float y0 = state[row0 * 7 + item];   // coalesced
            const float gp = goal - y0;

#pragma unroll
            for (int tt = 0; tt < 11; ++tt) {
                float p = TBL.v[tt * 8 + 3] * w_[0];
                p = fmaf(TBL.v[tt * 8 + 4], w_[1], p);
                p = fmaf(TBL.v[tt * 8 + 5], w_[2], p);
                p = fmaf(TBL.v[tt * 8 + 6], w_[3], p);
                p = fmaf(TBL.v[tt * 8 + 7], w_[4], p);
                float y = fmaf(TBL.v[tt * 8 + 0], y0, TBL.v[tt * 8 + 2]);
                y = fmaf(TBL.v[tt * 8 + 1], goal, y);
                y = fmaf(gp, p, y);
                L[lrow * 77 + tt * 7 + d] = y;         // OB overlays XT region
            }
        }
        __syncthreads();
        // flush 32 rows x 77 = 2464 floats = 616 float4, coalesced
#pragma unroll
        for (int i = 0; i < 3; ++i) {
            const int idx = i * 256 + tid;
            if (idx < 616) {
                const float4 v = *(const float4*)&L[idx * 4];
                *(float4*)(out + row0 * 77 + (size_t)pass * 2464 + (size_t)idx * 4) = v;
            }
        }
        __syncthreads();   // protect OB before next pass rewrites it
    }
}

extern "C" void kernel_launch(void* const* d_in, const int* in_sizes, int n_in,
                              void* d_out, int out_size, void* d_ws, size_t ws_size,
                              hipStream_t stream) {
    const float* x     = (const float*)d_in[0];  // [65536,256]
    const float* state = (const float*)d_in[1];  // [65536,7]
    const float* W     = (const float*)d_in[2];  // [256,42]
    const float* b     = (const float*)d_in[3];  // [42]
    float* out = (float*)d_out;

    dmp_fused_kernel<<<1024, 256, 0, stream>>>(x, state, W, b, out);
}

// Round 5
// 113.909 us; speedup vs baseline: 1.7295x; 1.0994x over previous
//
#include <hip/hip_runtime.h>
#include <math.h>

// DMPNet fused, MI355X. Closed-form DMP:
//   y_T = a_T*y0 + h_T*z0 + c_T*goal + (goal-y0)*(w . V_T)
// (coefficient table computed at compile time, folded as literals)
//
// R5: GEMM moved to the matrix pipe. R2-R4 showed the scalar-broadcast FMA
// GEMM is capped at ~40% VALU (SMEM W loads force lgkmcnt(0) drains).
// Now: setup kernel converts W -> f16 W^T[48][256] in d_ws (once);
// main kernel: per-wave 16 rows x 48 cols via mfma_f32_16x16x32_f16,
// B-frags = 24 L2-hit dwordx4 loads (held in VGPRs), A-frags from an
// f16-staged LDS x-tile, closed-form DMP epilogue, coalesced float4 flush.

typedef _Float16 half8 __attribute__((ext_vector_type(8)));
typedef _Float16 half4 __attribute__((ext_vector_type(4)));
typedef float f32x4 __attribute__((ext_vector_type(4)));

// ---------------- compile-time DMP coefficient table ----------------
constexpr double dexp(double z) {
    double t = z / 64.0;
    double s = 1.0, term = 1.0;
    for (int n = 1; n <= 14; ++n) { term *= t / (double)n; s += term; }
    for (int i = 0; i < 6; ++i) s *= s;   // ^64
    return s;
}

struct Tbl { float v[88]; };

constexpr Tbl make_tbl() {
    Tbl T{};
    double c[5] = {}, s2[5] = {};
    for (int i = 0; i < 5; ++i) {
        c[i]  = dexp(-0.25 * (double)i);
        s2[i] = 11.180339887498949 / c[i];       // 5^1.5 / c_i
    }
    double hh[101] = {}, aa[101] = {};
    // A^t, A = [[1, 0.01], [-0.5625, 0.85]] (sequential powers)
    double m00 = 1, m01 = 0, m10 = 0, m11 = 1;
    for (int t = 0; t <= 100; ++t) {
        hh[t] = m01; aa[t] = m00;
        const double n00 = m00 - 0.5625 * m01;
        const double n01 = 0.01 * m00 + 0.85 * m01;
        const double n10 = m10 - 0.5625 * m11;
        const double n11 = 0.01 * m10 + 0.85 * m11;
        m00 = n00; m01 = n01; m10 = n10; m11 = n11;
    }
    double vv[101][5] = {};
    double xs = 1.0;
    for (int s = 1; s <= 100; ++s) {
        xs *= 0.99;                               // canonical x_s = 0.99^s
        double psi[5] = {}, sum = 0.0;
        for (int i = 0; i < 5; ++i) {
            const double d = xs - c[i];
            psi[i] = dexp(-0.5 * d * d / s2[i]);
            sum += psi[i];
        }
        for (int i = 0; i < 5; ++i) vv[s][i] = psi[i] * xs / sum;
    }
    for (int tt = 0; tt < 11; ++tt) {
        const int T10 = 10 * tt;
        double cg = 0.0;
        for (int k = 0; k < T10; ++k) cg += hh[k];
        T.v[tt * 8 + 0] = (float)aa[T10];
        T.v[tt * 8 + 1] = (float)(0.5625 * cg);
        T.v[tt * 8 + 2] = (float)(hh[T10] * 0.05);   // z0 = dy0*TAU = 0.05
        for (int i = 0; i < 5; ++i) {
            double V = 0.0;
            for (int s = 1; s <= T10; ++s) V += hh[T10 - s] * vv[s][i];
            T.v[tt * 8 + 3 + i] = (float)(0.01 * V);
        }
    }
    return T;
}

constexpr Tbl TBL = make_tbl();

// ---------------- setup: W [256][42] fp32 -> W^T [48][256] f16 in d_ws ------
__global__ __launch_bounds__(256) void wt_setup_kernel(
    const float* __restrict__ W, _Float16* __restrict__ wt)
{
    __shared__ float s[10752];
    for (int f = threadIdx.x; f < 10752; f += 256) s[f] = W[f];   // coalesced
    __syncthreads();
    for (int o = threadIdx.x; o < 12288; o += 256) {
        const int col = o >> 8, k = o & 255;
        wt[o] = (col < 42) ? (_Float16)s[k * 42 + col] : (_Float16)0.f;
    }
}

// ---------------- main kernel ----------------
// 1024 blocks x 256 threads (4 waves). Block owns 64 rows; wave w owns rows
// [16w,16w+16), all K, 48 cols (3 MFMA accs). LDS (47104 B, 3 blocks/CU):
//   xt = [64][264] f16 x-tile, 33792 B  (reused as OB[64*77] f32 in epilogue)
//   P  = [64][52] f32 acc dump at +33792, 13312 B
__global__ __launch_bounds__(256, 3) void dmp_mfma_kernel(
    const float* __restrict__ x,       // [65536,256]
    const float* __restrict__ state,   // [65536,7]
    const _Float16* __restrict__ wt,   // [48][256] f16 (d_ws)
    const float* __restrict__ bias,    // [42]
    float* __restrict__ out)           // [65536,11,7]
{
    __shared__ __align__(16) char LDS[47104];
    _Float16* xt = (_Float16*)LDS;            // [64][264]
    float* P  = (float*)(LDS + 33792);        // [64][52]
    float* OB = (float*)LDS;                  // [64][77] (after xt is dead)

    const int tid  = threadIdx.x;
    const int wave = tid >> 6;
    const int lane = tid & 63;
    const int n    = lane & 15;               // MFMA n / m index
    const int quad = lane >> 4;
    const size_t row0 = (size_t)blockIdx.x * 64;
    const float* xb = x + row0 * 256;

    // ---- B fragments: 24 x half8, L2-resident, held in VGPRs ----
    // B[k = quad*8+j][col = 16t+n]  ->  wt[(16t+n)*256 + 32*iter + 8*quad + j]
    half8 bf[24];
#pragma unroll
    for (int it = 0; it < 8; ++it)
#pragma unroll
        for (int t = 0; t < 3; ++t)
            bf[it * 3 + t] =
                *(const half8*)(wt + (t * 16 + n) * 256 + it * 32 + quad * 8);

    // ---- stage x tile: fp32 coalesced -> f16 LDS [row][k], stride 264 ----
#pragma unroll
    for (int b = 0; b < 2; ++b) {
        float4 v[8];
#pragma unroll
        for (int j = 0; j < 8; ++j) {
            const int f = (b * 8 + j) * 256 + tid;          // float4 index
            v[j] = *(const float4*)(xb + (size_t)(f >> 6) * 256 + (f & 63) * 4);
        }
#pragma unroll
        for (int j = 0; j < 8; ++j) {
            const int f = (b * 8 + j) * 256 + tid;
            const int row = f >> 6, slot = f & 63;
            half4 h = { (_Float16)v[j].x, (_Float16)v[j].y,
                        (_Float16)v[j].z, (_Float16)v[j].w };
            *(half4*)(xt + row * 264 + slot * 4) = h;       // ds_write_b64
        }
    }
    __syncthreads();

    // ---- K-loop: 8 x (ds_read_b128 A-frag + 3 MFMA) ----
    f32x4 a0 = {0.f, 0.f, 0.f, 0.f};
    f32x4 a1 = {0.f, 0.f, 0.f, 0.f};
    f32x4 a2 = {0.f, 0.f, 0.f, 0.f};
    const int arow = wave * 16 + n;           // A: m = lane&15
#pragma unroll
    for (int it = 0; it < 8; ++it) {
        const half8 a = *(const half8*)(xt + arow * 264 + it * 32 + quad * 8);
        a0 = __builtin_amdgcn_mfma_f32_16x16x32_f16(a, bf[it * 3 + 0], a0, 0, 0, 0);
        a1 = __builtin_amdgcn_mfma_f32_16x16x32_f16(a, bf[it * 3 + 1], a1, 0, 0, 0);
        a2 = __builtin_amdgcn_mfma_f32_16x16x32_f16(a, bf[it * 3 + 2], a2, 0, 0, 0);
    }

    // ---- dump acc to P: row = 16w + quad*4 + r, col = n + 16t ----
    // stride 52: banks (16*quad + n) % 32 -> exact 2-way (free)
    const int prow = wave * 16 + quad * 4;
#pragma unroll
    for (int r = 0; r < 4; ++r) {
        P[(prow + r) * 52 + n]      = a0[r];
        P[(prow + r) * 52 + 16 + n] = a1[r];
        P[(prow + r) * 52 + 32 + n] = a2[r];
    }
    __syncthreads();

    // ---- closed-form DMP epilogue: 448 (row,dof) items -> OB ----
    for (int item = tid; item < 448; item += 256) {
        const int row = item / 7;
        const int d   = item - row * 7;
        const float goal = P[row * 52 + d] + bias[d];
        float w_[5];
#pragma unroll
        for (int i = 0; i < 5; ++i)
            w_[i] = P[row * 52 + 7 + 5 * d + i] + bias[7 + 5 * d + i];
        const float y0 = state[row0 * 7 + item];    // coalesced
        const float gp = goal - y0;
#pragma unroll
        for (int tt = 0; tt < 11; ++tt) {
            float p = TBL.v[tt * 8 + 3] * w_[0];
            p = fmaf(TBL.v[tt * 8 + 4], w_[1], p);
            p = fmaf(TBL.v[tt * 8 + 5], w_[2], p);
            p = fmaf(TBL.v[tt * 8 + 6], w_[3], p);
            p = fmaf(TBL.v[tt * 8 + 7], w_[4], p);
            float y = fmaf(TBL.v[tt * 8 + 0], y0, TBL.v[tt * 8 + 2]);
            y = fmaf(TBL.v[tt * 8 + 1], goal, y);
            y = fmaf(gp, p, y);
            OB[row * 77 + tt * 7 + d] = y;
        }
    }
    __syncthreads();

    // ---- coalesced float4 flush: 64 rows x 77 = 1232 float4 ----
#pragma unroll
    for (int i = 0; i < 5; ++i) {
        const int idx = i * 256 + tid;
        if (idx < 1232) {
            const float4 v = *(const float4*)(OB + idx * 4);
            *(float4*)(out + row0 * 77 + (size_t)idx * 4) = v;
        }
    }
}

extern "C" void kernel_launch(void* const* d_in, const int* in_sizes, int n_in,
                              void* d_out, int out_size, void* d_ws, size_t ws_size,
                              hipStream_t stream) {
    const float* x     = (const float*)d_in[0];  // [65536,256]
    const float* state = (const float*)d_in[1];  // [65536,7]
    const float* W     = (const float*)d_in[2];  // [256,42]
    const float* b     = (const float*)d_in[3];  // [42]
    _Float16* wt = (_Float16*)d_ws;              // 12288 f16 = 24576 B
    float* out = (float*)d_out;

    wt_setup_kernel<<<1, 256, 0, stream>>>(W, wt);
    dmp_mfma_kernel<<<1024, 256, 0, stream>>>(x, state, wt, b, out);
}

// Round 6
// 110.685 us; speedup vs baseline: 1.7799x; 1.0291x over previous
//
#include <hip/hip_runtime.h>
#include <math.h>

// DMPNet fused, MI355X. Closed-form DMP:
//   y_T = a_T*y0 + h_T*z0 + c_T*goal + (goal-y0)*(w . V_T)
// (coefficient table computed at compile time, folded as literals)
//
// R6: B-fragment path fixed. R5 loaded B-frags with per-lane addresses 512 B
// apart -> 64 cache lines per dwordx4, ~1536 TA line-lookups/wave/block --
// ~10 us of vector-memory pipe occupancy per CU. Now the setup kernel writes
// W into d_ws in PER-LANE FRAGMENT ORDER (wtf[frag][lane] = the half8 that
// lane needs), so the 24 B-frag loads are perfectly coalesced 1 KB reads.

typedef _Float16 half8 __attribute__((ext_vector_type(8)));
typedef _Float16 half4 __attribute__((ext_vector_type(4)));
typedef float f32x4 __attribute__((ext_vector_type(4)));

// ---------------- compile-time DMP coefficient table ----------------
constexpr double dexp(double z) {
    double t = z / 64.0;
    double s = 1.0, term = 1.0;
    for (int n = 1; n <= 14; ++n) { term *= t / (double)n; s += term; }
    for (int i = 0; i < 6; ++i) s *= s;   // ^64
    return s;
}

struct Tbl { float v[88]; };

constexpr Tbl make_tbl() {
    Tbl T{};
    double c[5] = {}, s2[5] = {};
    for (int i = 0; i < 5; ++i) {
        c[i]  = dexp(-0.25 * (double)i);
        s2[i] = 11.180339887498949 / c[i];       // 5^1.5 / c_i
    }
    double hh[101] = {}, aa[101] = {};
    // A^t, A = [[1, 0.01], [-0.5625, 0.85]] (sequential powers)
    double m00 = 1, m01 = 0, m10 = 0, m11 = 1;
    for (int t = 0; t <= 100; ++t) {
        hh[t] = m01; aa[t] = m00;
        const double n00 = m00 - 0.5625 * m01;
        const double n01 = 0.01 * m00 + 0.85 * m01;
        const double n10 = m10 - 0.5625 * m11;
        const double n11 = 0.01 * m10 + 0.85 * m11;
        m00 = n00; m01 = n01; m10 = n10; m11 = n11;
    }
    double vv[101][5] = {};
    double xs = 1.0;
    for (int s = 1; s <= 100; ++s) {
        xs *= 0.99;                               // canonical x_s = 0.99^s
        double psi[5] = {}, sum = 0.0;
        for (int i = 0; i < 5; ++i) {
            const double d = xs - c[i];
            psi[i] = dexp(-0.5 * d * d / s2[i]);
            sum += psi[i];
        }
        for (int i = 0; i < 5; ++i) vv[s][i] = psi[i] * xs / sum;
    }
    for (int tt = 0; tt < 11; ++tt) {
        const int T10 = 10 * tt;
        double cg = 0.0;
        for (int k = 0; k < T10; ++k) cg += hh[k];
        T.v[tt * 8 + 0] = (float)aa[T10];
        T.v[tt * 8 + 1] = (float)(0.5625 * cg);
        T.v[tt * 8 + 2] = (float)(hh[T10] * 0.05);   // z0 = dy0*TAU = 0.05
        for (int i = 0; i < 5; ++i) {
            double V = 0.0;
            for (int s = 1; s <= T10; ++s) V += hh[T10 - s] * vv[s][i];
            T.v[tt * 8 + 3 + i] = (float)(0.01 * V);
        }
    }
    return T;
}

constexpr Tbl TBL = make_tbl();

// ------- setup: W [256][42] fp32 -> f16 B-frags in per-lane order ----------
// wtf[fid*8 + j], fid = (it*3 + t)*64 + lane: the half8 for lane in frag
// (it,t):  element j = W[k = it*32 + (lane>>4)*8 + j][col = t*16 + (lane&15)]
// Grid: 2 blocks x 256; 1536 frags, 3 per thread, writes coalesced 16 B.
__global__ __launch_bounds__(256) void wt_setup_kernel(
    const float* __restrict__ W, _Float16* __restrict__ wtf)
{
    __shared__ float s[10752];
    for (int f = threadIdx.x; f < 10752; f += 256) s[f] = W[f];   // coalesced
    __syncthreads();
#pragma unroll
    for (int sb = 0; sb < 3; ++sb) {
        const int fid = sb * 512 + blockIdx.x * 256 + threadIdx.x;  // 0..1535
        const int lane = fid & 63;
        const int i    = fid >> 6;          // 0..23 = it*3 + t
        const int it   = i / 3, t = i - it * 3;
        const int col  = t * 16 + (lane & 15);
        const int k0   = it * 32 + (lane >> 4) * 8;
        half8 h;
#pragma unroll
        for (int j = 0; j < 8; ++j)
            h[j] = (col < 42) ? (_Float16)s[(k0 + j) * 42 + col] : (_Float16)0.f;
        *(half8*)(wtf + fid * 8) = h;
    }
}

// ---------------- main kernel ----------------
// 1024 blocks x 256 threads (4 waves). Block owns 64 rows; wave w owns rows
// [16w,16w+16), all K, 48 cols (3 MFMA accs). LDS (47104 B, 3 blocks/CU):
//   xt = [64][264] f16 x-tile, 33792 B  (reused as OB[64*77] f32 in epilogue)
//   P  = [64][52] f32 acc dump at +33792, 13312 B
__global__ __launch_bounds__(256, 3) void dmp_mfma_kernel(
    const float* __restrict__ x,       // [65536,256]
    const float* __restrict__ state,   // [65536,7]
    const _Float16* __restrict__ wtf,  // [24][64] half8 frags (d_ws)
    const float* __restrict__ bias,    // [42]
    float* __restrict__ out)           // [65536,11,7]
{
    __shared__ __align__(16) char LDS[47104];
    _Float16* xt = (_Float16*)LDS;            // [64][264]
    float* P  = (float*)(LDS + 33792);        // [64][52]
    float* OB = (float*)LDS;                  // [64][77] (after xt is dead)

    const int tid  = threadIdx.x;
    const int wave = tid >> 6;
    const int lane = tid & 63;
    const int n    = lane & 15;               // MFMA n / m index
    const int quad = lane >> 4;
    const size_t row0 = (size_t)blockIdx.x * 64;
    const float* xb = x + row0 * 256;

    // ---- start the HBM x-stream first: batch 0 of the tile loads ----
    float4 v0[8];
#pragma unroll
    for (int j = 0; j < 8; ++j) {
        const int f = j * 256 + tid;
        v0[j] = *(const float4*)(xb + (size_t)(f >> 6) * 256 + (f & 63) * 4);
    }

    // ---- B fragments: 24 coalesced 1 KB dwordx4 (L2-resident) ----
    half8 bf[24];
#pragma unroll
    for (int i = 0; i < 24; ++i)
        bf[i] = *(const half8*)(wtf + (i * 64 + lane) * 8);

    // ---- stage batch 0, load batch 1, stage batch 1 ----
#pragma unroll
    for (int j = 0; j < 8; ++j) {
        const int f = j * 256 + tid;
        const int row = f >> 6, slot = f & 63;
        half4 h = { (_Float16)v0[j].x, (_Float16)v0[j].y,
                    (_Float16)v0[j].z, (_Float16)v0[j].w };
        *(half4*)(xt + row * 264 + slot * 4) = h;       // ds_write_b64
    }
#pragma unroll
    for (int j = 0; j < 8; ++j) {
        const int f = (8 + j) * 256 + tid;
        v0[j] = *(const float4*)(xb + (size_t)(f >> 6) * 256 + (f & 63) * 4);
    }
#pragma unroll
    for (int j = 0; j < 8; ++j) {
        const int f = (8 + j) * 256 + tid;
        const int row = f >> 6, slot = f & 63;
        half4 h = { (_Float16)v0[j].x, (_Float16)v0[j].y,
                    (_Float16)v0[j].z, (_Float16)v0[j].w };
        *(half4*)(xt + row * 264 + slot * 4) = h;
    }
    __syncthreads();

    // ---- K-loop: 8 x (ds_read_b128 A-frag + 3 MFMA) ----
    f32x4 a0 = {0.f, 0.f, 0.f, 0.f};
    f32x4 a1 = {0.f, 0.f, 0.f, 0.f};
    f32x4 a2 = {0.f, 0.f, 0.f, 0.f};
    const int arow = wave * 16 + n;           // A: m = lane&15
#pragma unroll
    for (int it = 0; it < 8; ++it) {
        const half8 a = *(const half8*)(xt + arow * 264 + it * 32 + quad * 8);
        a0 = __builtin_amdgcn_mfma_f32_16x16x32_f16(a, bf[it * 3 + 0], a0, 0, 0, 0);
        a1 = __builtin_amdgcn_mfma_f32_16x16x32_f16(a, bf[it * 3 + 1], a1, 0, 0, 0);
        a2 = __builtin_amdgcn_mfma_f32_16x16x32_f16(a, bf[it * 3 + 2], a2, 0, 0, 0);
    }

    // ---- dump acc to P: row = 16w + quad*4 + r, col = n + 16t ----
    // stride 52: banks (16*quad + n) % 32 -> exact 2-way (free)
    const int prow = wave * 16 + quad * 4;
#pragma unroll
    for (int r = 0; r < 4; ++r) {
        P[(prow + r) * 52 + n]      = a0[r];
        P[(prow + r) * 52 + 16 + n] = a1[r];
        P[(prow + r) * 52 + 32 + n] = a2[r];
    }
    __syncthreads();

    // ---- closed-form DMP epilogue: 448 (row,dof) items -> OB ----
    for (int item = tid; item < 448; item += 256) {
        const int row = item / 7;
        const int d   = item - row * 7;
        const float goal = P[row * 52 + d] + bias[d];
        float w_[5];
#pragma unroll
        for (int i = 0; i < 5; ++i)
            w_[i] = P[row * 52 + 7 + 5 * d + i] + bias[7 + 5 * d + i];
        const float y0 = state[row0 * 7 + item];    // coalesced
        const float gp = goal - y0;
#pragma unroll
        for (int tt = 0; tt < 11; ++tt) {
            float p = TBL.v[tt * 8 + 3] * w_[0];
            p = fmaf(TBL.v[tt * 8 + 4], w_[1], p);
            p = fmaf(TBL.v[tt * 8 + 5], w_[2], p);
            p = fmaf(TBL.v[tt * 8 + 6], w_[3], p);
            p = fmaf(TBL.v[tt * 8 + 7], w_[4], p);
            float y = fmaf(TBL.v[tt * 8 + 0], y0, TBL.v[tt * 8 + 2]);
            y = fmaf(TBL.v[tt * 8 + 1], goal, y);
            y = fmaf(gp, p, y);
            OB[row * 77 + tt * 7 + d] = y;
        }
    }
    __syncthreads();

    // ---- coalesced float4 flush: 64 rows x 77 = 1232 float4 ----
#pragma unroll
    for (int i = 0; i < 5; ++i) {
        const int idx = i * 256 + tid;
        if (idx < 1232) {
            const float4 v = *(const float4*)(OB + idx * 4);
            *(float4*)(out + row0 * 77 + (size_t)idx * 4) = v;
        }
    }
}

extern "C" void kernel_launch(void* const* d_in, const int* in_sizes, int n_in,
                              void* d_out, int out_size, void* d_ws, size_t ws_size,
                              hipStream_t stream) {
    const float* x     = (const float*)d_in[0];  // [65536,256]
    const float* state = (const float*)d_in[1];  // [65536,7]
    const float* W     = (const float*)d_in[2];  // [256,42]
    const float* b     = (const float*)d_in[3];  // [42]
    _Float16* wtf = (_Float16*)d_ws;             // 12288 f16 = 24576 B
    float* out = (float*)d_out;

    wt_setup_kernel<<<2, 256, 0, stream>>>(W, wtf);
    dmp_mfma_kernel<<<1024, 256, 0, stream>>>(x, state, wtf, b, out);
}